// Round 1
// baseline (6135.778 us; speedup 1.0000x reference)
//
#include <hip/hip_runtime.h>
#include <math.h>

#define VOCAB  32000
#define EMB    256
#define HID    512
#define MAXLEN 512
#define BATCH  128
#define NCLASS 2

// ---------------------------------------------------------------------------
// Kernel A: embW[v][j] = b_h[j] + sum_e emb[v][e] * W_ih[e][j]
// Tile: 64 rows x 512 cols, K=256. 256 threads, micro-tile 8x16.
// grid = VOCAB/64 = 500 blocks.
// ---------------------------------------------------------------------------
__global__ __launch_bounds__(256, 1) void embw_kernel(
    const float* __restrict__ emb, const float* __restrict__ W_ih,
    const float* __restrict__ b_h, float* __restrict__ embW)
{
    __shared__ __align__(16) float aT[EMB][64];   // [e][row], 64 KB
    __shared__ __align__(16) float wS[32][HID];   // [ke][j],  64 KB

    const int t    = threadIdx.x;
    const int row0 = blockIdx.x * 64;

    // Stage A tile (transposed): 4 consecutive lanes cover 64B contiguous
    // global (coalesced); LDS writes have 4-way aliasing (cheap, one-time).
    {
        const int row   = t >> 2;        // 0..63
        const int elane = t & 3;         // 0..3
        for (int i = 0; i < 16; ++i) {
            const int e = elane * 4 + i * 16;
            const float4 v = *reinterpret_cast<const float4*>(
                &emb[(size_t)(row0 + row) * EMB + e]);
            aT[e + 0][row] = v.x;
            aT[e + 1][row] = v.y;
            aT[e + 2][row] = v.z;
            aT[e + 3][row] = v.w;
        }
    }

    const int rg = t >> 5;   // 0..7  row group (8 rows)
    const int cg = t & 31;   // 0..31 col group (16 cols)

    float acc[8][16];
    #pragma unroll
    for (int r = 0; r < 8; ++r)
        #pragma unroll
        for (int c = 0; c < 16; ++c) acc[r][c] = 0.f;

    for (int ec = 0; ec < 8; ++ec) {
        __syncthreads();  // protect wS against previous chunk's readers
        // Stage W chunk [32 e][512 j]: 128 lanes cover a 2KB row (coalesced)
        {
            const int j4  = (t & 127) * 4;
            const int keb = (t >> 7);        // 0..1
            #pragma unroll
            for (int i = 0; i < 16; ++i) {
                const int ke = keb + i * 2;
                const float4 v = *reinterpret_cast<const float4*>(
                    &W_ih[(size_t)(ec * 32 + ke) * HID + j4]);
                *reinterpret_cast<float4*>(&wS[ke][j4]) = v;
            }
        }
        __syncthreads();

        for (int ke = 0; ke < 32; ++ke) {
            float a8[8];
            *(float4*)&a8[0] = *(const float4*)&aT[ec * 32 + ke][rg * 8];
            *(float4*)&a8[4] = *(const float4*)&aT[ec * 32 + ke][rg * 8 + 4];
            float w16[16];
            #pragma unroll
            for (int q = 0; q < 4; ++q)
                *(float4*)&w16[q * 4] =
                    *(const float4*)&wS[ke][cg * 16 + q * 4];
            #pragma unroll
            for (int r = 0; r < 8; ++r)
                #pragma unroll
                for (int c = 0; c < 16; ++c)
                    acc[r][c] = fmaf(a8[r], w16[c], acc[r][c]);
        }
    }

    // Epilogue: += b_h, store
    float bh[16];
    #pragma unroll
    for (int q = 0; q < 4; ++q)
        *(float4*)&bh[q * 4] = *(const float4*)&b_h[cg * 16 + q * 4];
    #pragma unroll
    for (int r = 0; r < 8; ++r) {
        const size_t orow = (size_t)(row0 + rg * 8 + r) * HID + cg * 16;
        #pragma unroll
        for (int q = 0; q < 4; ++q) {
            float4 v;
            v.x = acc[r][q * 4 + 0] + bh[q * 4 + 0];
            v.y = acc[r][q * 4 + 1] + bh[q * 4 + 1];
            v.z = acc[r][q * 4 + 2] + bh[q * 4 + 2];
            v.w = acc[r][q * 4 + 3] + bh[q * 4 + 3];
            *reinterpret_cast<float4*>(&embW[orow + q * 4]) = v;
        }
    }
}

// ---------------------------------------------------------------------------
// Kernel B: sequential RNN. Block owns 2 batch rows (independent recurrence,
// no inter-block sync). 512 threads: thread j owns output column j.
// h double-buffered in LDS, interleaved [k][g] so one ds_read_b64 (broadcast)
// serves both batch rows. W_hh streamed from L2 each step.
// grid = BATCH/2 = 64 blocks.
// ---------------------------------------------------------------------------
__global__ __launch_bounds__(512, 1) void rnn_kernel(
    const int* __restrict__ inputs, const float* __restrict__ embW,
    const float* __restrict__ W_hh, float* __restrict__ h_final)
{
    __shared__ __align__(16) float hbuf[2][HID * 2];
    const int j  = threadIdx.x;
    const int b0 = blockIdx.x * 2;

    hbuf[0][j * 2]     = 0.f;
    hbuf[0][j * 2 + 1] = 0.f;
    __syncthreads();

    int cur = 0;
    for (int ts = 0; ts < MAXLEN; ++ts) {
        // feedforward term: gather precomputed embW rows (issued early,
        // consumed after the k-loop so the L3 latency hides under compute)
        const int tok0 = inputs[b0 * MAXLEN + ts];
        const int tok1 = inputs[(b0 + 1) * MAXLEN + ts];
        const float e0 = embW[(size_t)tok0 * HID + j];
        const float e1 = embW[(size_t)tok1 * HID + j];

        float acc0 = 0.f, acc1 = 0.f;
        const float* hc = hbuf[cur];
        #pragma unroll 8
        for (int k = 0; k < HID; ++k) {
            const float w  = W_hh[k * HID + j];              // coalesced row
            const float2 h2 = *reinterpret_cast<const float2*>(&hc[k * 2]);
            acc0 = fmaf(h2.x, w, acc0);
            acc1 = fmaf(h2.y, w, acc1);
        }
        const float t0 = tanhf(acc0 + e0);
        const float t1 = tanhf(acc1 + e1);
        *reinterpret_cast<float2*>(&hbuf[cur ^ 1][j * 2]) =
            make_float2(t0, t1);
        __syncthreads();   // single barrier/step (double buffer)
        cur ^= 1;
    }

    h_final[(size_t)b0 * HID + j]       = hbuf[cur][j * 2];
    h_final[(size_t)(b0 + 1) * HID + j] = hbuf[cur][j * 2 + 1];
}

// ---------------------------------------------------------------------------
// Kernel C: logits = h_final @ W_out + b_out, sigmoid. 1 block, 256 threads,
// thread = (batch, class). Tiny.
// ---------------------------------------------------------------------------
__global__ void head_kernel(const float* __restrict__ h_final,
                            const float* __restrict__ W_out,
                            const float* __restrict__ b_out,
                            float* __restrict__ out)
{
    const int t = threadIdx.x;        // 0..255
    const int b = t >> 1, c = t & 1;
    float acc = b_out[c];
    for (int k = 0; k < HID; ++k)
        acc = fmaf(h_final[(size_t)b * HID + k], W_out[k * NCLASS + c], acc);
    out[t] = 1.f / (1.f + expf(-acc));
}

// ---------------------------------------------------------------------------
extern "C" void kernel_launch(void* const* d_in, const int* in_sizes, int n_in,
                              void* d_out, int out_size, void* d_ws,
                              size_t ws_size, hipStream_t stream)
{
    const int*   inputs = (const int*)  d_in[0];
    const float* emb    = (const float*)d_in[1];
    const float* W_ih   = (const float*)d_in[2];
    const float* W_hh   = (const float*)d_in[3];
    const float* b_h    = (const float*)d_in[4];
    const float* W_out  = (const float*)d_in[5];
    const float* b_out  = (const float*)d_in[6];
    float* out = (float*)d_out;

    // workspace layout: embW (32000*512 f32 = 62.5 MiB) | h_final (256 KiB)
    float* embW    = (float*)d_ws;
    float* h_final = embW + (size_t)VOCAB * HID;

    embw_kernel<<<VOCAB / 64, 256, 0, stream>>>(emb, W_ih, b_h, embW);
    rnn_kernel<<<BATCH / 2, 512, 0, stream>>>(inputs, embW, W_hh, h_final);
    head_kernel<<<1, 256, 0, stream>>>(h_final, W_out, b_out, out);
}